// Round 13
// baseline (793.308 us; speedup 1.0000x reference)
//
#include <hip/hip_runtime.h>

// ---------------------------------------------------------------------------
// S = D = 4096 single-head attention (with the module's v-transpose bug).
// All six 4096^3 matmuls are NT GEMMs: C[m,n] = sum_k A[m,k]B[n,k].
// Round 13: ONE barrier per K-tile (publish vmcnt(0)+barrier at P1-end).
// All t+2 staging happens after the publish (P2/P3), reads stay one phase
// ahead (8/4/4/8), quadrant order Q00,Q10,Q01,Q11:
//   P0: read ahi(t)[8];                         MFMA Q00(alo,b0)
//   P1: read b1(t)[4];                          MFMA Q10(ahi,b0); publish
//   P2: read b0(t+1)[4]; stage A(t+2)h0+B(t+2)h0; MFMA Q01(alo,b1)
//   P3: read alo(t+1)[8]; stage A(t+2)h1+B(t+2)h1; MFMA Q11(ahi,b1)
// ---------------------------------------------------------------------------

typedef __attribute__((ext_vector_type(4))) float f32x4;
typedef __attribute__((ext_vector_type(8))) short short8;
typedef __attribute__((ext_vector_type(4))) unsigned short us4;

#define DIM 4096
#define NT  64   // K tiles of 64

__device__ __forceinline__ unsigned short f2bf(float f) {
    unsigned int u = __builtin_bit_cast(unsigned int, f);
    u += 0x7fffu + ((u >> 16) & 1u);   // round-to-nearest-even
    return (unsigned short)(u >> 16);
}

__device__ __forceinline__ float bf2f(unsigned short h) {
    return __builtin_bit_cast(float, (unsigned int)h << 16);
}

__device__ __forceinline__ void gll16(const void* g, void* l) {
    __builtin_amdgcn_global_load_lds(
        (const __attribute__((address_space(1))) unsigned int*)g,
        (__attribute__((address_space(3))) unsigned int*)l,
        16, 0, 0);
}

// ---------------------------------------------------------------------------
__global__ void cast_kernel(const float* __restrict__ in, unsigned short* __restrict__ out) {
    const size_t i = ((size_t)blockIdx.x * 256 + threadIdx.x) * 4;
    float4 x = *(const float4*)(in + i);
    us4 y;
    y.x = f2bf(x.x); y.y = f2bf(x.y); y.z = f2bf(x.z); y.w = f2bf(x.w);
    *(us4*)(out + i) = y;
}

// ---------------------------------------------------------------------------
// 256x256 NT GEMM, BK=64, 8 waves (2x4, wave tile 128x64), 128 KiB LDS dbuf,
// st_16x32 swizzle via pre-swizzled global source.
// WAR audit (stage region vs last read-issue; publish @P1-end in between):
//   A(t+2)h0 @P2 (A rows 0-127)   vs alo(t) reads @P3(t-1)  -> publish(t)
//   A(t+2)h1 @P3 (A rows 128-255) vs ahi(t) reads @P0(t)    -> publish(t)
//   B(t+2)h0 @P2 (B rows 0-127)   vs b0(t) reads @P2(t-1)   -> publish(t)
//   B(t+2)h1 @P3 (B rows 128-255) vs b1(t) reads @P1(t)     -> publish(t)
// Skew check: waves straddling publish(t) touch disjoint regions (h0 vs h1).
// Publish vmcnt(0) @P1-end: outstanding = exactly tile t+1's 8 units
// (staged P2/P3(t-1), 2-3 phases of flight) -> drain is cheap.
// EPI: 0 = bf16 out + bias            (projections)
//      1 = bf16 out exp(acc/64)       (E for softmax)
//      2 = f32 out + bias + bf16 res  (final; res = bf16 cast of raw value)
//      3 = bf16 out * rowscale[row]   (PV with softmax normalization)
// ---------------------------------------------------------------------------
template <int EPI>
__global__ __launch_bounds__(512, 2)
void gemm256(const unsigned short* __restrict__ A, const unsigned short* __restrict__ B,
             void* __restrict__ Cout, const float* __restrict__ bias,
             const unsigned short* __restrict__ resb, const float* __restrict__ rowscale) {
    __shared__ alignas(16) char lds[131072];

    const int tid = threadIdx.x;
    const int w = tid >> 6, l = tid & 63;
    const int wr = w >> 2, wc = w & 3;          // 2 x 4 waves, wave tile 128x64

    // bijective XCD swizzle (256 blocks, 8 XCDs)
    const int bid = blockIdx.x;
    const int swz = (bid & 7) * 32 + (bid >> 3);
    const int row0 = (swz >> 4) << 8;
    const int col0 = (swz & 15) << 8;

    // lane constants (st_16x32 layout)
    const int laneA  = (l & 15) * 64 + (((l >> 4) << 4) ^ ((l & 8) << 2)); // swizzled frag-read byte
    const int sl_row = l >> 2;                                  // staging row within subtile
    const int sl_col = ((l & 3) << 3) ^ ((l & 32) ? 16 : 0);    // staging col elem (inverse swz)

    f32x4 acc[8][4];
    const f32x4 zero = {0.f, 0.f, 0.f, 0.f};
#pragma unroll
    for (int m = 0; m < 8; ++m)
#pragma unroll
        for (int n = 0; n < 4; ++n) acc[m][n] = zero;

    char* const ldsp = (char*)lds;
    char* const A0 = ldsp;
    char* const B0 = ldsp + 32768;
    char* const A1 = ldsp + 65536;
    char* const B1 = ldsp + 98304;

    const int aoff = wr * 16384 + laneA;
    const int boff = wc * 8192 + laneA;

    // stage half-tile h of K-tile t into ldsMat: 2 gll16/thread (16 chunks/8 waves)
    auto stage = [&](const unsigned short* __restrict__ M, char* ldsMat, int rowbase,
                     int t, int h) {
        {
            const int rg = h * 8 + (w >> 1), cg = w & 1;
            gll16(M + (size_t)(rowbase + rg * 16 + sl_row) * DIM + t * 64 + cg * 32 + sl_col,
                  ldsMat + ((rg * 2 + cg) << 10));
        }
        {
            const int s = 8 + w;
            const int rg = h * 8 + (s >> 1), cg = s & 1;
            gll16(M + (size_t)(rowbase + rg * 16 + sl_row) * DIM + t * 64 + cg * 32 + sl_col,
                  ldsMat + ((rg * 2 + cg) << 10));
        }
    };

    short8 alo[4][2], ahi[4][2], b0[2][2], b1[2][2];

    // ---- prologue: stage tiles 0 and 1 fully; land tile 0; pre-read alo,b0 ----
    stage(A, A0, row0, 0, 0); stage(A, A0, row0, 0, 1);
    stage(B, B0, col0, 0, 0); stage(B, B0, col0, 0, 1);
    stage(A, A1, row0, 1, 0); stage(A, A1, row0, 1, 1);
    stage(B, B1, col0, 1, 0); stage(B, B1, col0, 1, 1);
    asm volatile("s_waitcnt vmcnt(8)\ns_barrier" ::: "memory");   // tile0 landed
#pragma unroll
    for (int m2 = 0; m2 < 4; ++m2)
#pragma unroll
        for (int ks = 0; ks < 2; ++ks)
            alo[m2][ks] = *(const short8*)(A0 + aoff + ((m2 * 2 + ks) << 10));
#pragma unroll
    for (int n2 = 0; n2 < 2; ++n2)
#pragma unroll
        for (int ks = 0; ks < 2; ++ks)
            b0[n2][ks] = *(const short8*)(B0 + boff + ((n2 * 2 + ks) << 10));

    // one K-tile; Abuf/Bbuf = buf(t) (read + t+2 staging target); An/Bn = buf(t+1)
    auto body = [&](int t, char* Abuf, char* Bbuf, const char* An, const char* Bn) {
        const int t2 = (t + 2 < NT) ? t + 2 : NT - 1;   // tail scribbles dead slots

        // ---- P0: read ahi(t) [8]; MFMA Q00(alo,b0) ----
#pragma unroll
        for (int m2 = 0; m2 < 4; ++m2)
#pragma unroll
            for (int ks = 0; ks < 2; ++ks)
                ahi[m2][ks] = *(const short8*)(Abuf + aoff + (((4 + m2) * 2 + ks) << 10));
        __builtin_amdgcn_s_setprio(1);
#pragma unroll
        for (int m2 = 0; m2 < 4; ++m2)
#pragma unroll
            for (int n2 = 0; n2 < 2; ++n2)
#pragma unroll
                for (int ks = 0; ks < 2; ++ks)
                    acc[m2][n2] = __builtin_amdgcn_mfma_f32_16x16x32_bf16(
                        alo[m2][ks], b0[n2][ks], acc[m2][n2], 0, 0, 0);
        __builtin_amdgcn_s_setprio(0);

        // ---- P1: read b1(t) [4]; MFMA Q10(ahi,b0); publish tile t+1 ----
#pragma unroll
        for (int n2 = 0; n2 < 2; ++n2)
#pragma unroll
            for (int ks = 0; ks < 2; ++ks)
                b1[n2][ks] = *(const short8*)(Bbuf + boff + (((2 + n2) * 2 + ks) << 10));
        __builtin_amdgcn_s_setprio(1);
#pragma unroll
        for (int m2 = 0; m2 < 4; ++m2)
#pragma unroll
            for (int n2 = 0; n2 < 2; ++n2)
#pragma unroll
                for (int ks = 0; ks < 2; ++ks)
                    acc[4 + m2][n2] = __builtin_amdgcn_mfma_f32_16x16x32_bf16(
                        ahi[m2][ks], b0[n2][ks], acc[4 + m2][n2], 0, 0, 0);
        __builtin_amdgcn_s_setprio(0);
        // publish: the only outstanding loads are tile t+1's 8 units -> drain;
        // all tile-t reads of regions staged next (P2/P3) were issued above.
        asm volatile("s_waitcnt vmcnt(0)\ns_barrier" ::: "memory");

        // ---- P2: read b0(t+1) [4]; stage A(t+2)h0 + B(t+2)h0; MFMA Q01(alo,b1) ----
#pragma unroll
        for (int n2 = 0; n2 < 2; ++n2)
#pragma unroll
            for (int ks = 0; ks < 2; ++ks)
                b0[n2][ks] = *(const short8*)(Bn + boff + ((n2 * 2 + ks) << 10));
        stage(A, Abuf, row0, t2, 0);
        stage(B, Bbuf, col0, t2, 0);
        __builtin_amdgcn_s_setprio(1);
#pragma unroll
        for (int m2 = 0; m2 < 4; ++m2)
#pragma unroll
            for (int n2 = 0; n2 < 2; ++n2)
#pragma unroll
                for (int ks = 0; ks < 2; ++ks)
                    acc[m2][2 + n2] = __builtin_amdgcn_mfma_f32_16x16x32_bf16(
                        alo[m2][ks], b1[n2][ks], acc[m2][2 + n2], 0, 0, 0);
        __builtin_amdgcn_s_setprio(0);

        // ---- P3: read alo(t+1) [8]; stage A(t+2)h1 + B(t+2)h1; MFMA Q11(ahi,b1) ----
#pragma unroll
        for (int m2 = 0; m2 < 4; ++m2)
#pragma unroll
            for (int ks = 0; ks < 2; ++ks)
                alo[m2][ks] = *(const short8*)(An + aoff + ((m2 * 2 + ks) << 10));
        stage(A, Abuf, row0, t2, 1);
        stage(B, Bbuf, col0, t2, 1);
        __builtin_amdgcn_s_setprio(1);
#pragma unroll
        for (int m2 = 0; m2 < 4; ++m2)
#pragma unroll
            for (int n2 = 0; n2 < 2; ++n2)
#pragma unroll
                for (int ks = 0; ks < 2; ++ks)
                    acc[4 + m2][2 + n2] = __builtin_amdgcn_mfma_f32_16x16x32_bf16(
                        ahi[m2][ks], b1[n2][ks], acc[4 + m2][2 + n2], 0, 0, 0);
        __builtin_amdgcn_s_setprio(0);
    };

#pragma unroll 1
    for (int tt = 0; tt < NT / 2; ++tt) {
        const int t = 2 * tt;
        body(t,     A0, B0, A1, B1);
        body(t + 1, A1, B1, A0, B0);
    }
    asm volatile("s_waitcnt vmcnt(0)" ::: "memory");

    // ---- epilogue: D col = lane&15, row = (lane>>4)*4 + r ----
#pragma unroll
    for (int mf = 0; mf < 8; ++mf) {
        const int grow0 = row0 + wr * 128 + mf * 16 + ((l >> 4) << 2);
#pragma unroll
        for (int nf = 0; nf < 4; ++nf) {
            const int gcol = col0 + wc * 64 + nf * 16 + (l & 15);
            float bias_v = 0.f;
            if constexpr (EPI == 0 || EPI == 2) {
                bias_v = bias[gcol];
            }
#pragma unroll
            for (int r = 0; r < 4; ++r) {
                const int grow = grow0 + r;
                const size_t idx = (size_t)grow * DIM + gcol;
                const float a = acc[mf][nf][r];
                if constexpr (EPI == 0) {
                    ((unsigned short*)Cout)[idx] = f2bf(a + bias_v);
                } else if constexpr (EPI == 1) {
                    ((unsigned short*)Cout)[idx] = f2bf(__expf(a * 0.015625f));
                } else if constexpr (EPI == 2) {
                    ((float*)Cout)[idx] = a + bias_v + bf2f(resb[idx]);
                } else {
                    ((unsigned short*)Cout)[idx] = f2bf(a * rowscale[grow]);
                }
            }
        }
    }
}

// ---------------------------------------------------------------------------
// Row sum of E (bf16) -> invs[row] = 1/sum. One block (256 thr) per row.
// ---------------------------------------------------------------------------
__global__ __launch_bounds__(256)
void rowsum_kernel(const unsigned short* __restrict__ E, float* __restrict__ invs) {
    const int row = blockIdx.x;
    const int t = threadIdx.x;
    const unsigned short* src = E + (size_t)row * DIM + t * 16;

    float s = 0.f;
#pragma unroll
    for (int j = 0; j < 2; ++j) {
        short8 v = *(const short8*)(src + j * 8);
#pragma unroll
        for (int e = 0; e < 8; ++e)
            s += bf2f((unsigned short)v[e]);
    }
#pragma unroll
    for (int off = 32; off > 0; off >>= 1) s += __shfl_xor(s, off);

    __shared__ float red[4];
    if ((t & 63) == 0) red[t >> 6] = s;
    __syncthreads();
    if (t == 0) {
        const float tot = (red[0] + red[1]) + (red[2] + red[3]);
        invs[row] = 1.0f / tot;
    }
}

// ---------------------------------------------------------------------------
extern "C" void kernel_launch(void* const* d_in, const int* in_sizes, int n_in,
                              void* d_out, int out_size, void* d_ws, size_t ws_size,
                              hipStream_t stream) {
    const float* query = (const float*)d_in[0];
    const float* key   = (const float*)d_in[1];
    const float* value = (const float*)d_in[2];
    const float* Wq    = (const float*)d_in[3];
    const float* bq    = (const float*)d_in[4];
    const float* Wk    = (const float*)d_in[5];
    const float* bk    = (const float*)d_in[6];
    const float* Wv    = (const float*)d_in[7];
    const float* bv    = (const float*)d_in[8];
    const float* Wo    = (const float*)d_in[9];
    const float* bo    = (const float*)d_in[10];

    const size_t SZ = (size_t)DIM * DIM;
    unsigned short* qb   = (unsigned short*)d_ws;
    unsigned short* kb   = qb + SZ;
    unsigned short* vb   = kb + SZ;
    unsigned short* xb   = vb + SZ;          // reused cast buffer (inputs); after the
                                             // v-projection step it holds bf16(value)
                                             // and is NOT overwritten afterwards.
    unsigned short* wb   = xb + SZ;          // reused cast buffer (weights)
    unsigned short* Eb   = wb + SZ;          // E = exp(logits) bf16
    unsigned short* ctxb = Eb + SZ;
    float* invs = (float*)(ctxb + SZ);       // 4096 f32
    // total ws use: 7*SZ*2 + 16KB = 235 MB

    const dim3 cg(16384), cb(256);
    const dim3 gg(256), gb(512);

    // q = query @ Wq.T + bq
    cast_kernel<<<cg, cb, 0, stream>>>(query, xb);
    cast_kernel<<<cg, cb, 0, stream>>>(Wq, wb);
    gemm256<0><<<gg, gb, 0, stream>>>(xb, wb, qb, bq, nullptr, nullptr);
    // k = key @ Wk.T + bk
    cast_kernel<<<cg, cb, 0, stream>>>(key, xb);
    cast_kernel<<<cg, cb, 0, stream>>>(Wk, wb);
    gemm256<0><<<gg, gb, 0, stream>>>(xb, wb, kb, bk, nullptr, nullptr);
    // v = value @ Wv.T + bv   (xb keeps bf16(value) for the final residual)
    cast_kernel<<<cg, cb, 0, stream>>>(value, xb);
    cast_kernel<<<cg, cb, 0, stream>>>(Wv, wb);
    gemm256<0><<<gg, gb, 0, stream>>>(xb, wb, vb, bv, nullptr, nullptr);
    // E = exp((q @ k.T)/64)   (bf16; no max-sub needed, max logit ~9)
    gemm256<1><<<gg, gb, 0, stream>>>(qb, kb, Eb, nullptr, nullptr, nullptr);
    // invs[row] = 1/rowsum(E)
    rowsum_kernel<<<4096, 256, 0, stream>>>(Eb, invs);
    // ctx = softmax(scores) @ v.T = (E @ v.T) * invs[row]
    gemm256<3><<<gg, gb, 0, stream>>>(Eb, vb, ctxb, nullptr, nullptr, invs);
    // out = ctx @ Wo.T + bo + value   (residual = bf16 cast of RAW value, in xb)
    cast_kernel<<<cg, cb, 0, stream>>>(Wo, wb);
    gemm256<2><<<gg, gb, 0, stream>>>(ctxb, wb, d_out, bo, xb, nullptr);
}

// Round 14
// 790.560 us; speedup vs baseline: 1.0035x; 1.0035x over previous
//
#include <hip/hip_runtime.h>

// ---------------------------------------------------------------------------
// S = D = 4096 single-head attention (with the module's v-transpose bug).
// All six 4096^3 matmuls are NT GEMMs: C[m,n] = sum_k A[m,k]B[n,k].
// Round 14: r13 1-barrier/tile GEMM loop, minus XCD swizzle (inputs are
// L3-fit; m160: swizzle costs ~2% when L3-fit), plus deterministic rowsum
// fusion: E-GEMM epilogue emits per-block row partials (fp32, pre-rounding),
// tiny invs kernel folds 16 partials -> 1/sum. No atomics (replay determinism).
// ---------------------------------------------------------------------------

typedef __attribute__((ext_vector_type(4))) float f32x4;
typedef __attribute__((ext_vector_type(8))) short short8;
typedef __attribute__((ext_vector_type(4))) unsigned short us4;

#define DIM 4096
#define NT  64   // K tiles of 64

__device__ __forceinline__ unsigned short f2bf(float f) {
    unsigned int u = __builtin_bit_cast(unsigned int, f);
    u += 0x7fffu + ((u >> 16) & 1u);   // round-to-nearest-even
    return (unsigned short)(u >> 16);
}

__device__ __forceinline__ float bf2f(unsigned short h) {
    return __builtin_bit_cast(float, (unsigned int)h << 16);
}

__device__ __forceinline__ void gll16(const void* g, void* l) {
    __builtin_amdgcn_global_load_lds(
        (const __attribute__((address_space(1))) unsigned int*)g,
        (__attribute__((address_space(3))) unsigned int*)l,
        16, 0, 0);
}

// ---------------------------------------------------------------------------
__global__ void cast_kernel(const float* __restrict__ in, unsigned short* __restrict__ out) {
    const size_t i = ((size_t)blockIdx.x * 256 + threadIdx.x) * 4;
    float4 x = *(const float4*)(in + i);
    us4 y;
    y.x = f2bf(x.x); y.y = f2bf(x.y); y.z = f2bf(x.z); y.w = f2bf(x.w);
    *(us4*)(out + i) = y;
}

// ---------------------------------------------------------------------------
// 256x256 NT GEMM, BK=64, 8 waves (2x4, wave tile 128x64), LDS 132 KiB
// (128 KiB dbuf + 4 KiB reduce slab), st_16x32 swizzle via pre-swizzled
// global source. ONE barrier per K-tile (publish vmcnt(0)+barrier @P1-end):
//   P0: read ahi(t)[8];                           MFMA Q00(alo,b0)
//   P1: read b1(t)[4];                            MFMA Q10(ahi,b0); publish
//   P2: read b0(t+1)[4]; stage A(t+2)h0+B(t+2)h0; MFMA Q01(alo,b1)
//   P3: read alo(t+1)[8]; stage A(t+2)h1+B(t+2)h1; MFMA Q11(ahi,b1)
// EPI: 0 = bf16 out + bias            (projections)
//      1 = bf16 out exp(acc/64) + per-block fp32 row-partial sums
//      2 = f32 out + bias + bf16 res  (final; res = bf16 cast of raw value)
//      3 = bf16 out * rowscale[row]   (PV with softmax normalization)
// ---------------------------------------------------------------------------
template <int EPI>
__global__ __launch_bounds__(512, 2)
void gemm256(const unsigned short* __restrict__ A, const unsigned short* __restrict__ B,
             void* __restrict__ Cout, const float* __restrict__ bias,
             const unsigned short* __restrict__ resb, const float* __restrict__ rowscale,
             float* __restrict__ partial) {
    __shared__ alignas(16) char lds[131072 + 4096];

    const int tid = threadIdx.x;
    const int w = tid >> 6, l = tid & 63;
    const int wr = w >> 2, wc = w & 3;          // 2 x 4 waves, wave tile 128x64

    // no XCD swizzle: inputs are L3-fit (64 MB), m160: swizzle costs ~2% here
    const int bid = blockIdx.x;
    const int row0 = (bid >> 4) << 8;
    const int col0 = (bid & 15) << 8;

    // lane constants (st_16x32 layout)
    const int laneA  = (l & 15) * 64 + (((l >> 4) << 4) ^ ((l & 8) << 2)); // swizzled frag-read byte
    const int sl_row = l >> 2;                                  // staging row within subtile
    const int sl_col = ((l & 3) << 3) ^ ((l & 32) ? 16 : 0);    // staging col elem (inverse swz)

    f32x4 acc[8][4];
    const f32x4 zero = {0.f, 0.f, 0.f, 0.f};
#pragma unroll
    for (int m = 0; m < 8; ++m)
#pragma unroll
        for (int n = 0; n < 4; ++n) acc[m][n] = zero;

    char* const ldsp = (char*)lds;
    char* const A0 = ldsp;
    char* const B0 = ldsp + 32768;
    char* const A1 = ldsp + 65536;
    char* const B1 = ldsp + 98304;
    float* const smem = (float*)(ldsp + 131072);   // [4][256] reduce slab

    const int aoff = wr * 16384 + laneA;
    const int boff = wc * 8192 + laneA;

    // stage half-tile h of K-tile t into ldsMat: 2 gll16/thread (16 chunks/8 waves)
    auto stage = [&](const unsigned short* __restrict__ M, char* ldsMat, int rowbase,
                     int t, int h) {
        {
            const int rg = h * 8 + (w >> 1), cg = w & 1;
            gll16(M + (size_t)(rowbase + rg * 16 + sl_row) * DIM + t * 64 + cg * 32 + sl_col,
                  ldsMat + ((rg * 2 + cg) << 10));
        }
        {
            const int s = 8 + w;
            const int rg = h * 8 + (s >> 1), cg = s & 1;
            gll16(M + (size_t)(rowbase + rg * 16 + sl_row) * DIM + t * 64 + cg * 32 + sl_col,
                  ldsMat + ((rg * 2 + cg) << 10));
        }
    };

    short8 alo[4][2], ahi[4][2], b0[2][2], b1[2][2];

    // ---- prologue: stage tiles 0 and 1 fully; land tile 0; pre-read alo,b0 ----
    stage(A, A0, row0, 0, 0); stage(A, A0, row0, 0, 1);
    stage(B, B0, col0, 0, 0); stage(B, B0, col0, 0, 1);
    stage(A, A1, row0, 1, 0); stage(A, A1, row0, 1, 1);
    stage(B, B1, col0, 1, 0); stage(B, B1, col0, 1, 1);
    asm volatile("s_waitcnt vmcnt(8)\ns_barrier" ::: "memory");   // tile0 landed
#pragma unroll
    for (int m2 = 0; m2 < 4; ++m2)
#pragma unroll
        for (int ks = 0; ks < 2; ++ks)
            alo[m2][ks] = *(const short8*)(A0 + aoff + ((m2 * 2 + ks) << 10));
#pragma unroll
    for (int n2 = 0; n2 < 2; ++n2)
#pragma unroll
        for (int ks = 0; ks < 2; ++ks)
            b0[n2][ks] = *(const short8*)(B0 + boff + ((n2 * 2 + ks) << 10));

    // one K-tile; Abuf/Bbuf = buf(t) (read + t+2 staging target); An/Bn = buf(t+1)
    auto body = [&](int t, char* Abuf, char* Bbuf, const char* An, const char* Bn) {
        const int t2 = (t + 2 < NT) ? t + 2 : NT - 1;   // tail scribbles dead slots

        // ---- P0: read ahi(t) [8]; MFMA Q00(alo,b0) ----
#pragma unroll
        for (int m2 = 0; m2 < 4; ++m2)
#pragma unroll
            for (int ks = 0; ks < 2; ++ks)
                ahi[m2][ks] = *(const short8*)(Abuf + aoff + (((4 + m2) * 2 + ks) << 10));
        __builtin_amdgcn_s_setprio(1);
#pragma unroll
        for (int m2 = 0; m2 < 4; ++m2)
#pragma unroll
            for (int n2 = 0; n2 < 2; ++n2)
#pragma unroll
                for (int ks = 0; ks < 2; ++ks)
                    acc[m2][n2] = __builtin_amdgcn_mfma_f32_16x16x32_bf16(
                        alo[m2][ks], b0[n2][ks], acc[m2][n2], 0, 0, 0);
        __builtin_amdgcn_s_setprio(0);

        // ---- P1: read b1(t) [4]; MFMA Q10(ahi,b0); publish tile t+1 ----
#pragma unroll
        for (int n2 = 0; n2 < 2; ++n2)
#pragma unroll
            for (int ks = 0; ks < 2; ++ks)
                b1[n2][ks] = *(const short8*)(Bbuf + boff + (((2 + n2) * 2 + ks) << 10));
        __builtin_amdgcn_s_setprio(1);
#pragma unroll
        for (int m2 = 0; m2 < 4; ++m2)
#pragma unroll
            for (int n2 = 0; n2 < 2; ++n2)
#pragma unroll
                for (int ks = 0; ks < 2; ++ks)
                    acc[4 + m2][n2] = __builtin_amdgcn_mfma_f32_16x16x32_bf16(
                        ahi[m2][ks], b0[n2][ks], acc[4 + m2][n2], 0, 0, 0);
        __builtin_amdgcn_s_setprio(0);
        // publish: only outstanding loads are tile t+1's 8 units -> drain
        asm volatile("s_waitcnt vmcnt(0)\ns_barrier" ::: "memory");

        // ---- P2: read b0(t+1) [4]; stage A(t+2)h0 + B(t+2)h0; MFMA Q01(alo,b1) ----
#pragma unroll
        for (int n2 = 0; n2 < 2; ++n2)
#pragma unroll
            for (int ks = 0; ks < 2; ++ks)
                b0[n2][ks] = *(const short8*)(Bn + boff + ((n2 * 2 + ks) << 10));
        stage(A, Abuf, row0, t2, 0);
        stage(B, Bbuf, col0, t2, 0);
        __builtin_amdgcn_s_setprio(1);
#pragma unroll
        for (int m2 = 0; m2 < 4; ++m2)
#pragma unroll
            for (int n2 = 0; n2 < 2; ++n2)
#pragma unroll
                for (int ks = 0; ks < 2; ++ks)
                    acc[m2][2 + n2] = __builtin_amdgcn_mfma_f32_16x16x32_bf16(
                        alo[m2][ks], b1[n2][ks], acc[m2][2 + n2], 0, 0, 0);
        __builtin_amdgcn_s_setprio(0);

        // ---- P3: read alo(t+1) [8]; stage A(t+2)h1 + B(t+2)h1; MFMA Q11(ahi,b1) ----
#pragma unroll
        for (int m2 = 0; m2 < 4; ++m2)
#pragma unroll
            for (int ks = 0; ks < 2; ++ks)
                alo[m2][ks] = *(const short8*)(An + aoff + ((m2 * 2 + ks) << 10));
        stage(A, Abuf, row0, t2, 1);
        stage(B, Bbuf, col0, t2, 1);
        __builtin_amdgcn_s_setprio(1);
#pragma unroll
        for (int m2 = 0; m2 < 4; ++m2)
#pragma unroll
            for (int n2 = 0; n2 < 2; ++n2)
#pragma unroll
                for (int ks = 0; ks < 2; ++ks)
                    acc[4 + m2][2 + n2] = __builtin_amdgcn_mfma_f32_16x16x32_bf16(
                        ahi[m2][ks], b1[n2][ks], acc[4 + m2][2 + n2], 0, 0, 0);
        __builtin_amdgcn_s_setprio(0);
    };

#pragma unroll 1
    for (int tt = 0; tt < NT / 2; ++tt) {
        const int t = 2 * tt;
        body(t,     A0, B0, A1, B1);
        body(t + 1, A1, B1, A0, B0);
    }
    asm volatile("s_waitcnt vmcnt(0)" ::: "memory");   // drain dead tail DMAs too

    // ---- epilogue: D col = lane&15, row = (lane>>4)*4 + r ----
    if constexpr (EPI == 1) __syncthreads();   // LDS reads done everywhere; smem safe
#pragma unroll
    for (int mf = 0; mf < 8; ++mf) {
        const int grow0 = row0 + wr * 128 + mf * 16 + ((l >> 4) << 2);
        float rs[4] = {0.f, 0.f, 0.f, 0.f};
#pragma unroll
        for (int nf = 0; nf < 4; ++nf) {
            const int gcol = col0 + wc * 64 + nf * 16 + (l & 15);
            float bias_v = 0.f;
            if constexpr (EPI == 0 || EPI == 2) {
                bias_v = bias[gcol];
            }
#pragma unroll
            for (int r = 0; r < 4; ++r) {
                const int grow = grow0 + r;
                const size_t idx = (size_t)grow * DIM + gcol;
                const float a = acc[mf][nf][r];
                if constexpr (EPI == 0) {
                    ((unsigned short*)Cout)[idx] = f2bf(a + bias_v);
                } else if constexpr (EPI == 1) {
                    const float e = __expf(a * 0.015625f);
                    rs[r] += e;
                    ((unsigned short*)Cout)[idx] = f2bf(e);
                } else if constexpr (EPI == 2) {
                    ((float*)Cout)[idx] = a + bias_v + bf2f(resb[idx]);
                } else {
                    ((unsigned short*)Cout)[idx] = f2bf(a * rowscale[grow]);
                }
            }
        }
        if constexpr (EPI == 1) {
            // reduce each row partial across the 16 lanes sharing the row
#pragma unroll
            for (int r = 0; r < 4; ++r) {
                float s = rs[r];
                s += __shfl_xor(s, 1); s += __shfl_xor(s, 2);
                s += __shfl_xor(s, 4); s += __shfl_xor(s, 8);
                if ((l & 15) == 0)
                    smem[wc * 256 + wr * 128 + mf * 16 + ((l >> 4) << 2) + r] = s;
            }
        }
    }
    if constexpr (EPI == 1) {
        __syncthreads();
        if (tid < 256) {
            const float s = smem[tid] + smem[256 + tid] + smem[512 + tid] + smem[768 + tid];
            partial[(size_t)(col0 >> 8) * DIM + row0 + tid] = s;
        }
    }
}

// ---------------------------------------------------------------------------
// invs[row] = 1 / sum over 16 col-block partials. 16 blocks x 256 threads.
// ---------------------------------------------------------------------------
__global__ __launch_bounds__(256)
void invs_kernel(const float* __restrict__ partial, float* __restrict__ invs) {
    const int row = blockIdx.x * 256 + threadIdx.x;
    float s = 0.f;
#pragma unroll
    for (int cb = 0; cb < 16; ++cb)
        s += partial[(size_t)cb * DIM + row];
    invs[row] = 1.0f / s;
}

// ---------------------------------------------------------------------------
extern "C" void kernel_launch(void* const* d_in, const int* in_sizes, int n_in,
                              void* d_out, int out_size, void* d_ws, size_t ws_size,
                              hipStream_t stream) {
    const float* query = (const float*)d_in[0];
    const float* key   = (const float*)d_in[1];
    const float* value = (const float*)d_in[2];
    const float* Wq    = (const float*)d_in[3];
    const float* bq    = (const float*)d_in[4];
    const float* Wk    = (const float*)d_in[5];
    const float* bk    = (const float*)d_in[6];
    const float* Wv    = (const float*)d_in[7];
    const float* bv    = (const float*)d_in[8];
    const float* Wo    = (const float*)d_in[9];
    const float* bo    = (const float*)d_in[10];

    const size_t SZ = (size_t)DIM * DIM;
    unsigned short* qb   = (unsigned short*)d_ws;
    unsigned short* kb   = qb + SZ;
    unsigned short* vb   = kb + SZ;
    unsigned short* xb   = vb + SZ;          // reused cast buffer (inputs); after the
                                             // v-projection step it holds bf16(value)
    unsigned short* wb   = xb + SZ;          // reused cast buffer (weights)
    unsigned short* Eb   = wb + SZ;          // E = exp(logits) bf16
    unsigned short* ctxb = Eb + SZ;
    float* invs    = (float*)(ctxb + SZ);    // 4096 f32
    float* partial = invs + DIM;             // 16 x 4096 f32

    const dim3 cg(16384), cb(256);
    const dim3 gg(256), gb(512);

    // q = query @ Wq.T + bq
    cast_kernel<<<cg, cb, 0, stream>>>(query, xb);
    cast_kernel<<<cg, cb, 0, stream>>>(Wq, wb);
    gemm256<0><<<gg, gb, 0, stream>>>(xb, wb, qb, bq, nullptr, nullptr, nullptr);
    // k = key @ Wk.T + bk
    cast_kernel<<<cg, cb, 0, stream>>>(key, xb);
    cast_kernel<<<cg, cb, 0, stream>>>(Wk, wb);
    gemm256<0><<<gg, gb, 0, stream>>>(xb, wb, kb, bk, nullptr, nullptr, nullptr);
    // v = value @ Wv.T + bv   (xb keeps bf16(value) for the final residual)
    cast_kernel<<<cg, cb, 0, stream>>>(value, xb);
    cast_kernel<<<cg, cb, 0, stream>>>(Wv, wb);
    gemm256<0><<<gg, gb, 0, stream>>>(xb, wb, vb, bv, nullptr, nullptr, nullptr);
    // E = exp((q @ k.T)/64) bf16 + fp32 per-block row partial sums
    gemm256<1><<<gg, gb, 0, stream>>>(qb, kb, Eb, nullptr, nullptr, nullptr, partial);
    // invs[row] = 1/rowsum
    invs_kernel<<<16, 256, 0, stream>>>(partial, invs);
    // ctx = softmax(scores) @ v.T = (E @ v.T) * invs[row]
    gemm256<3><<<gg, gb, 0, stream>>>(Eb, vb, ctxb, nullptr, nullptr, invs, nullptr);
    // out = ctx @ Wo.T + bo + value   (residual = bf16 cast of RAW value, in xb)
    cast_kernel<<<cg, cb, 0, stream>>>(Wo, wb);
    gemm256<2><<<gg, gb, 0, stream>>>(ctxb, wb, d_out, bo, xb, nullptr, nullptr);
}

// Round 15
// 778.869 us; speedup vs baseline: 1.0185x; 1.0150x over previous
//
#include <hip/hip_runtime.h>

// ---------------------------------------------------------------------------
// S = D = 4096 single-head attention (with the module's v-transpose bug).
// All six 4096^3 matmuls are NT GEMMs: C[m,n] = sum_k A[m,k]B[n,k].
// Round 15: r13 GEMM config (1 barrier/tile + bijective XCD swizzle, the
// best-measured combo) + r14's fused rowsum + merged cast launches (cast2).
// ---------------------------------------------------------------------------

typedef __attribute__((ext_vector_type(4))) float f32x4;
typedef __attribute__((ext_vector_type(8))) short short8;
typedef __attribute__((ext_vector_type(4))) unsigned short us4;

#define DIM 4096
#define NT  64   // K tiles of 64

__device__ __forceinline__ unsigned short f2bf(float f) {
    unsigned int u = __builtin_bit_cast(unsigned int, f);
    u += 0x7fffu + ((u >> 16) & 1u);   // round-to-nearest-even
    return (unsigned short)(u >> 16);
}

__device__ __forceinline__ float bf2f(unsigned short h) {
    return __builtin_bit_cast(float, (unsigned int)h << 16);
}

__device__ __forceinline__ void gll16(const void* g, void* l) {
    __builtin_amdgcn_global_load_lds(
        (const __attribute__((address_space(1))) unsigned int*)g,
        (__attribute__((address_space(3))) unsigned int*)l,
        16, 0, 0);
}

// ---------------------------------------------------------------------------
// cast2: casts two independent 16.7M-element fp32 arrays in one launch.
// blocks 0..16383 -> (in0,out0); 16384..32767 -> (in1,out1).
// ---------------------------------------------------------------------------
__global__ void cast2_kernel(const float* __restrict__ in0, unsigned short* __restrict__ out0,
                             const float* __restrict__ in1, unsigned short* __restrict__ out1) {
    const int b = blockIdx.x;
    const float* in = (b < 16384) ? in0 : in1;
    unsigned short* out = (b < 16384) ? out0 : out1;
    const size_t i = ((size_t)(b & 16383) * 256 + threadIdx.x) * 4;
    float4 x = *(const float4*)(in + i);
    us4 y;
    y.x = f2bf(x.x); y.y = f2bf(x.y); y.z = f2bf(x.z); y.w = f2bf(x.w);
    *(us4*)(out + i) = y;
}

__global__ void cast_kernel(const float* __restrict__ in, unsigned short* __restrict__ out) {
    const size_t i = ((size_t)blockIdx.x * 256 + threadIdx.x) * 4;
    float4 x = *(const float4*)(in + i);
    us4 y;
    y.x = f2bf(x.x); y.y = f2bf(x.y); y.z = f2bf(x.z); y.w = f2bf(x.w);
    *(us4*)(out + i) = y;
}

// ---------------------------------------------------------------------------
// 256x256 NT GEMM, BK=64, 8 waves (2x4, wave tile 128x64), LDS 132 KiB
// (128 KiB dbuf + 4 KiB reduce slab), st_16x32 swizzle via pre-swizzled
// global source, bijective XCD blockIdx swizzle. ONE barrier per K-tile
// (publish vmcnt(0)+barrier @P1-end):
//   P0: read ahi(t)[8];                           MFMA Q00(alo,b0)
//   P1: read b1(t)[4];                            MFMA Q10(ahi,b0); publish
//   P2: read b0(t+1)[4]; stage A(t+2)h0+B(t+2)h0; MFMA Q01(alo,b1)
//   P3: read alo(t+1)[8]; stage A(t+2)h1+B(t+2)h1; MFMA Q11(ahi,b1)
// EPI: 0 = bf16 out + bias            (projections)
//      1 = bf16 out exp(acc/64) + per-block fp32 row-partial sums
//      2 = f32 out + bias + bf16 res  (final; res = bf16 cast of raw value)
//      3 = bf16 out * rowscale[row]   (PV with softmax normalization)
// ---------------------------------------------------------------------------
template <int EPI>
__global__ __launch_bounds__(512, 2)
void gemm256(const unsigned short* __restrict__ A, const unsigned short* __restrict__ B,
             void* __restrict__ Cout, const float* __restrict__ bias,
             const unsigned short* __restrict__ resb, const float* __restrict__ rowscale,
             float* __restrict__ partial) {
    __shared__ alignas(16) char lds[131072 + 4096];

    const int tid = threadIdx.x;
    const int w = tid >> 6, l = tid & 63;
    const int wr = w >> 2, wc = w & 3;          // 2 x 4 waves, wave tile 128x64

    // bijective XCD swizzle (256 blocks, 8 XCDs) — r13's best-measured config
    const int bid = blockIdx.x;
    const int swz = (bid & 7) * 32 + (bid >> 3);
    const int row0 = (swz >> 4) << 8;
    const int col0 = (swz & 15) << 8;

    // lane constants (st_16x32 layout)
    const int laneA  = (l & 15) * 64 + (((l >> 4) << 4) ^ ((l & 8) << 2)); // swizzled frag-read byte
    const int sl_row = l >> 2;                                  // staging row within subtile
    const int sl_col = ((l & 3) << 3) ^ ((l & 32) ? 16 : 0);    // staging col elem (inverse swz)

    f32x4 acc[8][4];
    const f32x4 zero = {0.f, 0.f, 0.f, 0.f};
#pragma unroll
    for (int m = 0; m < 8; ++m)
#pragma unroll
        for (int n = 0; n < 4; ++n) acc[m][n] = zero;

    char* const ldsp = (char*)lds;
    char* const A0 = ldsp;
    char* const B0 = ldsp + 32768;
    char* const A1 = ldsp + 65536;
    char* const B1 = ldsp + 98304;
    float* const smem = (float*)(ldsp + 131072);   // [4][256] reduce slab

    const int aoff = wr * 16384 + laneA;
    const int boff = wc * 8192 + laneA;

    // stage half-tile h of K-tile t into ldsMat: 2 gll16/thread (16 chunks/8 waves)
    auto stage = [&](const unsigned short* __restrict__ M, char* ldsMat, int rowbase,
                     int t, int h) {
        {
            const int rg = h * 8 + (w >> 1), cg = w & 1;
            gll16(M + (size_t)(rowbase + rg * 16 + sl_row) * DIM + t * 64 + cg * 32 + sl_col,
                  ldsMat + ((rg * 2 + cg) << 10));
        }
        {
            const int s = 8 + w;
            const int rg = h * 8 + (s >> 1), cg = s & 1;
            gll16(M + (size_t)(rowbase + rg * 16 + sl_row) * DIM + t * 64 + cg * 32 + sl_col,
                  ldsMat + ((rg * 2 + cg) << 10));
        }
    };

    short8 alo[4][2], ahi[4][2], b0[2][2], b1[2][2];

    // ---- prologue: stage tiles 0 and 1 fully; land tile 0; pre-read alo,b0 ----
    stage(A, A0, row0, 0, 0); stage(A, A0, row0, 0, 1);
    stage(B, B0, col0, 0, 0); stage(B, B0, col0, 0, 1);
    stage(A, A1, row0, 1, 0); stage(A, A1, row0, 1, 1);
    stage(B, B1, col0, 1, 0); stage(B, B1, col0, 1, 1);
    asm volatile("s_waitcnt vmcnt(8)\ns_barrier" ::: "memory");   // tile0 landed
#pragma unroll
    for (int m2 = 0; m2 < 4; ++m2)
#pragma unroll
        for (int ks = 0; ks < 2; ++ks)
            alo[m2][ks] = *(const short8*)(A0 + aoff + ((m2 * 2 + ks) << 10));
#pragma unroll
    for (int n2 = 0; n2 < 2; ++n2)
#pragma unroll
        for (int ks = 0; ks < 2; ++ks)
            b0[n2][ks] = *(const short8*)(B0 + boff + ((n2 * 2 + ks) << 10));

    // one K-tile; Abuf/Bbuf = buf(t) (read + t+2 staging target); An/Bn = buf(t+1)
    auto body = [&](int t, char* Abuf, char* Bbuf, const char* An, const char* Bn) {
        const int t2 = (t + 2 < NT) ? t + 2 : NT - 1;   // tail scribbles dead slots

        // ---- P0: read ahi(t) [8]; MFMA Q00(alo,b0) ----
#pragma unroll
        for (int m2 = 0; m2 < 4; ++m2)
#pragma unroll
            for (int ks = 0; ks < 2; ++ks)
                ahi[m2][ks] = *(const short8*)(Abuf + aoff + (((4 + m2) * 2 + ks) << 10));
        __builtin_amdgcn_s_setprio(1);
#pragma unroll
        for (int m2 = 0; m2 < 4; ++m2)
#pragma unroll
            for (int n2 = 0; n2 < 2; ++n2)
#pragma unroll
                for (int ks = 0; ks < 2; ++ks)
                    acc[m2][n2] = __builtin_amdgcn_mfma_f32_16x16x32_bf16(
                        alo[m2][ks], b0[n2][ks], acc[m2][n2], 0, 0, 0);
        __builtin_amdgcn_s_setprio(0);

        // ---- P1: read b1(t) [4]; MFMA Q10(ahi,b0); publish tile t+1 ----
#pragma unroll
        for (int n2 = 0; n2 < 2; ++n2)
#pragma unroll
            for (int ks = 0; ks < 2; ++ks)
                b1[n2][ks] = *(const short8*)(Bbuf + boff + (((2 + n2) * 2 + ks) << 10));
        __builtin_amdgcn_s_setprio(1);
#pragma unroll
        for (int m2 = 0; m2 < 4; ++m2)
#pragma unroll
            for (int n2 = 0; n2 < 2; ++n2)
#pragma unroll
                for (int ks = 0; ks < 2; ++ks)
                    acc[4 + m2][n2] = __builtin_amdgcn_mfma_f32_16x16x32_bf16(
                        ahi[m2][ks], b0[n2][ks], acc[4 + m2][n2], 0, 0, 0);
        __builtin_amdgcn_s_setprio(0);
        // publish: only outstanding loads are tile t+1's 8 units -> drain
        asm volatile("s_waitcnt vmcnt(0)\ns_barrier" ::: "memory");

        // ---- P2: read b0(t+1) [4]; stage A(t+2)h0 + B(t+2)h0; MFMA Q01(alo,b1) ----
#pragma unroll
        for (int n2 = 0; n2 < 2; ++n2)
#pragma unroll
            for (int ks = 0; ks < 2; ++ks)
                b0[n2][ks] = *(const short8*)(Bn + boff + ((n2 * 2 + ks) << 10));
        stage(A, Abuf, row0, t2, 0);
        stage(B, Bbuf, col0, t2, 0);
        __builtin_amdgcn_s_setprio(1);
#pragma unroll
        for (int m2 = 0; m2 < 4; ++m2)
#pragma unroll
            for (int n2 = 0; n2 < 2; ++n2)
#pragma unroll
                for (int ks = 0; ks < 2; ++ks)
                    acc[m2][2 + n2] = __builtin_amdgcn_mfma_f32_16x16x32_bf16(
                        alo[m2][ks], b1[n2][ks], acc[m2][2 + n2], 0, 0, 0);
        __builtin_amdgcn_s_setprio(0);

        // ---- P3: read alo(t+1) [8]; stage A(t+2)h1 + B(t+2)h1; MFMA Q11(ahi,b1) ----
#pragma unroll
        for (int m2 = 0; m2 < 4; ++m2)
#pragma unroll
            for (int ks = 0; ks < 2; ++ks)
                alo[m2][ks] = *(const short8*)(An + aoff + ((m2 * 2 + ks) << 10));
        stage(A, Abuf, row0, t2, 1);
        stage(B, Bbuf, col0, t2, 1);
        __builtin_amdgcn_s_setprio(1);
#pragma unroll
        for (int m2 = 0; m2 < 4; ++m2)
#pragma unroll
            for (int n2 = 0; n2 < 2; ++n2)
#pragma unroll
                for (int ks = 0; ks < 2; ++ks)
                    acc[4 + m2][2 + n2] = __builtin_amdgcn_mfma_f32_16x16x32_bf16(
                        ahi[m2][ks], b1[n2][ks], acc[4 + m2][2 + n2], 0, 0, 0);
        __builtin_amdgcn_s_setprio(0);
    };

#pragma unroll 1
    for (int tt = 0; tt < NT / 2; ++tt) {
        const int t = 2 * tt;
        body(t,     A0, B0, A1, B1);
        body(t + 1, A1, B1, A0, B0);
    }
    asm volatile("s_waitcnt vmcnt(0)" ::: "memory");   // drain dead tail DMAs too

    // ---- epilogue: D col = lane&15, row = (lane>>4)*4 + r ----
    if constexpr (EPI == 1) __syncthreads();   // LDS reads done everywhere; smem safe
#pragma unroll
    for (int mf = 0; mf < 8; ++mf) {
        const int grow0 = row0 + wr * 128 + mf * 16 + ((l >> 4) << 2);
        float rs[4] = {0.f, 0.f, 0.f, 0.f};
#pragma unroll
        for (int nf = 0; nf < 4; ++nf) {
            const int gcol = col0 + wc * 64 + nf * 16 + (l & 15);
            float bias_v = 0.f;
            if constexpr (EPI == 0 || EPI == 2) {
                bias_v = bias[gcol];
            }
#pragma unroll
            for (int r = 0; r < 4; ++r) {
                const int grow = grow0 + r;
                const size_t idx = (size_t)grow * DIM + gcol;
                const float a = acc[mf][nf][r];
                if constexpr (EPI == 0) {
                    ((unsigned short*)Cout)[idx] = f2bf(a + bias_v);
                } else if constexpr (EPI == 1) {
                    const float e = __expf(a * 0.015625f);
                    rs[r] += e;
                    ((unsigned short*)Cout)[idx] = f2bf(e);
                } else if constexpr (EPI == 2) {
                    ((float*)Cout)[idx] = a + bias_v + bf2f(resb[idx]);
                } else {
                    ((unsigned short*)Cout)[idx] = f2bf(a * rowscale[grow]);
                }
            }
        }
        if constexpr (EPI == 1) {
            // reduce each row partial across the 16 lanes sharing the row
#pragma unroll
            for (int r = 0; r < 4; ++r) {
                float s = rs[r];
                s += __shfl_xor(s, 1); s += __shfl_xor(s, 2);
                s += __shfl_xor(s, 4); s += __shfl_xor(s, 8);
                if ((l & 15) == 0)
                    smem[wc * 256 + wr * 128 + mf * 16 + ((l >> 4) << 2) + r] = s;
            }
        }
    }
    if constexpr (EPI == 1) {
        __syncthreads();
        if (tid < 256) {
            const float s = smem[tid] + smem[256 + tid] + smem[512 + tid] + smem[768 + tid];
            partial[(size_t)(col0 >> 8) * DIM + row0 + tid] = s;
        }
    }
}

// ---------------------------------------------------------------------------
// invs[row] = 1 / sum over 16 col-block partials. 16 blocks x 256 threads.
// ---------------------------------------------------------------------------
__global__ __launch_bounds__(256)
void invs_kernel(const float* __restrict__ partial, float* __restrict__ invs) {
    const int row = blockIdx.x * 256 + threadIdx.x;
    float s = 0.f;
#pragma unroll
    for (int cb = 0; cb < 16; ++cb)
        s += partial[(size_t)cb * DIM + row];
    invs[row] = 1.0f / s;
}

// ---------------------------------------------------------------------------
extern "C" void kernel_launch(void* const* d_in, const int* in_sizes, int n_in,
                              void* d_out, int out_size, void* d_ws, size_t ws_size,
                              hipStream_t stream) {
    const float* query = (const float*)d_in[0];
    const float* key   = (const float*)d_in[1];
    const float* value = (const float*)d_in[2];
    const float* Wq    = (const float*)d_in[3];
    const float* bq    = (const float*)d_in[4];
    const float* Wk    = (const float*)d_in[5];
    const float* bk    = (const float*)d_in[6];
    const float* Wv    = (const float*)d_in[7];
    const float* bv    = (const float*)d_in[8];
    const float* Wo    = (const float*)d_in[9];
    const float* bo    = (const float*)d_in[10];

    const size_t SZ = (size_t)DIM * DIM;
    unsigned short* qb   = (unsigned short*)d_ws;
    unsigned short* kb   = qb + SZ;
    unsigned short* vb   = kb + SZ;
    unsigned short* xb   = vb + SZ;          // reused cast buffer (inputs); after the
                                             // v-projection step it holds bf16(value)
    unsigned short* wb   = xb + SZ;          // reused cast buffer (weights)
    unsigned short* Eb   = wb + SZ;          // E = exp(logits) bf16
    unsigned short* ctxb = Eb + SZ;
    float* invs    = (float*)(ctxb + SZ);    // 4096 f32
    float* partial = invs + DIM;             // 16 x 4096 f32

    const dim3 c2g(32768), cg(16384), cb(256);
    const dim3 gg(256), gb(512);

    // q = query @ Wq.T + bq
    cast2_kernel<<<c2g, cb, 0, stream>>>(query, xb, Wq, wb);
    gemm256<0><<<gg, gb, 0, stream>>>(xb, wb, qb, bq, nullptr, nullptr, nullptr);
    // k = key @ Wk.T + bk
    cast2_kernel<<<c2g, cb, 0, stream>>>(key, xb, Wk, wb);
    gemm256<0><<<gg, gb, 0, stream>>>(xb, wb, kb, bk, nullptr, nullptr, nullptr);
    // v = value @ Wv.T + bv   (xb keeps bf16(value) for the final residual)
    cast2_kernel<<<c2g, cb, 0, stream>>>(value, xb, Wv, wb);
    gemm256<0><<<gg, gb, 0, stream>>>(xb, wb, vb, bv, nullptr, nullptr, nullptr);
    // E = exp((q @ k.T)/64) bf16 + fp32 per-block row partial sums
    gemm256<1><<<gg, gb, 0, stream>>>(qb, kb, Eb, nullptr, nullptr, nullptr, partial);
    // invs[row] = 1/rowsum
    invs_kernel<<<16, 256, 0, stream>>>(partial, invs);
    // ctx = softmax(scores) @ v.T = (E @ v.T) * invs[row]
    gemm256<3><<<gg, gb, 0, stream>>>(Eb, vb, ctxb, nullptr, nullptr, invs, nullptr);
    // out = ctx @ Wo.T + bo + value   (residual = bf16 cast of RAW value, in xb)
    cast_kernel<<<cg, cb, 0, stream>>>(Wo, wb);
    gemm256<2><<<gg, gb, 0, stream>>>(ctxb, wb, d_out, bo, xb, nullptr, nullptr);
}